// Round 1
// baseline (513.798 us; speedup 1.0000x reference)
//
#include <hip/hip_runtime.h>
#include <hip/hip_bf16.h>
#include <cstdint>

typedef __attribute__((ext_vector_type(8))) short short8;
typedef __attribute__((ext_vector_type(4))) float floatx4;

#define NC   5
#define PP   196
#define DD   384
#define MM   512
#define ROWS (MM * PP)     /* 100352 = 784 * 128 exactly */
#define NRB  784
#define EPSN 1e-12f
#define LDSTR 40           /* LDS row stride in bf16 elems: 80B -> 16B-aligned frags, conflict-free */

/* monotone float <-> uint encoding so atomicMax(unsigned) orders like float */
__device__ __forceinline__ unsigned enc_f(float f) {
    unsigned u = __float_as_uint(f);
    return (u & 0x80000000u) ? ~u : (u | 0x80000000u);
}
__device__ __forceinline__ float dec_f(unsigned u) {
    unsigned b = (u & 0x80000000u) ? (u ^ 0x80000000u) : ~u;
    return __uint_as_float(b);
}
#define ENC_NEG_INF 0x007FFFFFu

/* ---- pass 1a: l2-normalize support rows -> bf16 ---- */
__global__ __launch_bounds__(256) void k_norm_support(const float* __restrict__ sup,
                                                      __hip_bfloat16* __restrict__ sn) {
    int wid = threadIdx.x >> 6, lane = threadIdx.x & 63;
    int r = blockIdx.x * 4 + wid;
    if (r >= NC * PP) return;
    const float* src = sup + (size_t)r * DD;
    float x[6]; float s = 0.f;
    #pragma unroll
    for (int j = 0; j < 6; ++j) { x[j] = src[lane + j * 64]; s += x[j] * x[j]; }
    #pragma unroll
    for (int off = 1; off < 64; off <<= 1) s += __shfl_xor(s, off, 64);
    float inv = 1.0f / fmaxf(sqrtf(s), EPSN);
    __hip_bfloat16* dst = sn + (size_t)r * DD;
    #pragma unroll
    for (int j = 0; j < 6; ++j) dst[lane + j * 64] = __float2bfloat16(x[j] * inv);
}

/* ---- pass 1b: 1/||q_row|| for every query row ---- */
__global__ __launch_bounds__(256) void k_qnorm(const float* __restrict__ q,
                                               float* __restrict__ invq, int nrows) {
    int gw = blockIdx.x * 4 + (threadIdx.x >> 6);
    int lane = threadIdx.x & 63;
    int nw = gridDim.x * 4;
    for (int r = gw; r < nrows; r += nw) {
        const float* src = q + (size_t)r * DD;
        float s = 0.f;
        #pragma unroll
        for (int j = 0; j < 6; ++j) { float v = src[lane + j * 64]; s += v * v; }
        #pragma unroll
        for (int off = 1; off < 64; off <<= 1) s += __shfl_xor(s, off, 64);
        if (lane == 0) invq[r] = 1.0f / fmaxf(sqrtf(s), EPSN);
    }
}

/* ---- main: 128-row strip x one class; two 128-col halves serially;
        mfma 16x16x32 bf16, 4 waves 2x2 each 64x64; fused col-max epilogue ---- */
__global__ __launch_bounds__(256) void k_gemm_max(const float* __restrict__ q,
                                                  const __hip_bfloat16* __restrict__ sn,
                                                  const float* __restrict__ invq,
                                                  float* __restrict__ rowmaxg) {
    __shared__ __hip_bfloat16 As[128 * LDSTR];
    __shared__ __hip_bfloat16 Bs[128 * LDSTR];
    __shared__ unsigned rmax[128];

    const int tid  = threadIdx.x;
    const int rb   = blockIdx.x / NC;
    const int c    = blockIdx.x % NC;
    const int row0 = rb * 128;

    if (tid < 128) rmax[tid] = ENC_NEG_INF;

    const int wav  = tid >> 6, lane = tid & 63;
    const int wr   = (wav >> 1) * 64;   /* wave row offset   */
    const int wc   = (wav & 1)  * 64;   /* wave col offset   */
    const int quad = lane >> 4, c16 = lane & 15;

    /* staging: thread t covers LDS row t>>1, k-halves of 16 */
    const int srow  = tid >> 1;
    const int skoff = (tid & 1) * 16;
    const float* aSrc = q + (size_t)(row0 + srow) * DD + skoff;

    for (int h = 0; h < 2; ++h) {
        floatx4 acc[4][4];
        #pragma unroll
        for (int i = 0; i < 4; ++i) {
            #pragma unroll
            for (int j = 0; j < 4; ++j) acc[i][j] = (floatx4){0.f, 0.f, 0.f, 0.f};
        }

        const int colBase = h * 128;                 /* class-local col of Bs row 0 */
        const int bcol    = colBase + srow;
        const bool bvalid = bcol < PP;
        const __hip_bfloat16* bSrc =
            sn + (size_t)(c * PP + (bvalid ? bcol : 0)) * DD + skoff;

        for (int kk = 0; kk < DD; kk += 32) {
            __syncthreads();
            /* ---- stage A (fp32 -> bf16) ---- */
            const float4* ap = (const float4*)(aSrc + kk);
            float4 A0 = ap[0], A1 = ap[1], A2 = ap[2], A3 = ap[3];
            alignas(16) __hip_bfloat16 hb[16];
            hb[0]  = __float2bfloat16(A0.x); hb[1]  = __float2bfloat16(A0.y);
            hb[2]  = __float2bfloat16(A0.z); hb[3]  = __float2bfloat16(A0.w);
            hb[4]  = __float2bfloat16(A1.x); hb[5]  = __float2bfloat16(A1.y);
            hb[6]  = __float2bfloat16(A1.z); hb[7]  = __float2bfloat16(A1.w);
            hb[8]  = __float2bfloat16(A2.x); hb[9]  = __float2bfloat16(A2.y);
            hb[10] = __float2bfloat16(A2.z); hb[11] = __float2bfloat16(A2.w);
            hb[12] = __float2bfloat16(A3.x); hb[13] = __float2bfloat16(A3.y);
            hb[14] = __float2bfloat16(A3.z); hb[15] = __float2bfloat16(A3.w);
            __hip_bfloat16* adst = &As[srow * LDSTR + skoff];
            *(uint4*)(adst)     = *(const uint4*)(hb);
            *(uint4*)(adst + 8) = *(const uint4*)(hb + 8);
            /* ---- stage B (bf16 copy, zero-pad cols >= 196) ---- */
            uint4 b0 = make_uint4(0u, 0u, 0u, 0u), b1 = b0;
            if (bvalid) {
                const uint4* bp = (const uint4*)(bSrc + kk);
                b0 = bp[0]; b1 = bp[1];
            }
            __hip_bfloat16* bdst = &Bs[srow * LDSTR + skoff];
            *(uint4*)(bdst)     = b0;
            *(uint4*)(bdst + 8) = b1;
            __syncthreads();
            /* ---- compute: 16 MFMAs / wave ---- */
            short8 a[4], b[4];
            #pragma unroll
            for (int rt = 0; rt < 4; ++rt)
                a[rt] = *(const short8*)&As[(wr + rt * 16 + c16) * LDSTR + quad * 8];
            #pragma unroll
            for (int ct = 0; ct < 4; ++ct)
                b[ct] = *(const short8*)&Bs[(wc + ct * 16 + c16) * LDSTR + quad * 8];
            #pragma unroll
            for (int rt = 0; rt < 4; ++rt) {
                #pragma unroll
                for (int ct = 0; ct < 4; ++ct)
                    acc[rt][ct] = __builtin_amdgcn_mfma_f32_16x16x32_bf16(
                        a[rt], b[ct], acc[rt][ct], 0, 0, 0);
            }
        }

        /* ---- epilogue: masked col-max for this half ---- */
        #pragma unroll
        for (int rt = 0; rt < 4; ++rt) {
            #pragma unroll
            for (int reg = 0; reg < 4; ++reg) {
                float mx = -INFINITY;
                #pragma unroll
                for (int ct = 0; ct < 4; ++ct) {
                    int col = colBase + wc + ct * 16 + c16;
                    float v = acc[rt][ct][reg];
                    mx = fmaxf(mx, (col < PP) ? v : -INFINITY);
                }
                #pragma unroll
                for (int off = 1; off < 16; off <<= 1)
                    mx = fmaxf(mx, __shfl_xor(mx, off, 64));
                if (c16 == 0) {
                    int rloc = wr + rt * 16 + quad * 4 + reg;
                    atomicMax(&rmax[rloc], enc_f(mx));
                }
            }
        }
    }

    __syncthreads();
    if (tid < 128) {
        int row = row0 + tid;
        float v = dec_f(rmax[tid]) * invq[row];   /* divide by ||q|| after the max */
        rowmaxg[(size_t)row * NC + c] = v;
    }
}

/* ---- top-6 sum per (m, c): one wave each ---- */
__global__ __launch_bounds__(256) void k_top6(const float* __restrict__ rowmaxg,
                                              const float* __restrict__ scale,
                                              const float* __restrict__ bias,
                                              float* __restrict__ out) {
    int wav = threadIdx.x >> 6, lane = threadIdx.x & 63;
    int pair = blockIdx.x * 4 + wav;
    if (pair >= MM * NC) return;
    int m = pair / NC, c = pair % NC;
    size_t base = (size_t)m * PP;
    float v[4];
    #pragma unroll
    for (int i = 0; i < 4; ++i) {
        int p = lane + i * 64;
        v[i] = (p < PP) ? rowmaxg[(base + p) * NC + c] : -INFINITY;
    }
    float sum = 0.f;
    for (int t = 0; t < 6; ++t) {
        float bv = v[0]; int bi = 0;
        #pragma unroll
        for (int i = 1; i < 4; ++i) { if (v[i] > bv) { bv = v[i]; bi = i; } }
        int gid = bi * 64 + lane;
        #pragma unroll
        for (int off = 1; off < 64; off <<= 1) {
            float ov = __shfl_xor(bv, off, 64);
            int og  = __shfl_xor(gid, off, 64);
            if (ov > bv || (ov == bv && og < gid)) { bv = ov; gid = og; }
        }
        sum += bv;
        if ((gid & 63) == lane) v[gid >> 6] = -INFINITY;  /* kill exactly one */
    }
    if (lane == 0) out[pair] = scale[0] * (sum + bias[0]);
}

extern "C" void kernel_launch(void* const* d_in, const int* in_sizes, int n_in,
                              void* d_out, int out_size, void* d_ws, size_t ws_size,
                              hipStream_t stream) {
    const float* support = (const float*)d_in[0];
    const float* query   = (const float*)d_in[1];
    const float* scale   = (const float*)d_in[2];
    const float* bias    = (const float*)d_in[3];
    float* out = (float*)d_out;

    char* ws = (char*)d_ws;
    __hip_bfloat16* sn = (__hip_bfloat16*)ws;                    /* 980*384*2   = 752640 -> pad 753664 */
    float* invq        = (float*)(ws + 753664);                  /* 100352*4    = 401408 */
    float* rowmaxg     = (float*)(ws + 753664 + 401408);         /* 100352*5*4  = 2007040 */

    hipLaunchKernelGGL(k_norm_support, dim3(245),      dim3(256), 0, stream, support, sn);
    hipLaunchKernelGGL(k_qnorm,        dim3(1024),     dim3(256), 0, stream, query, invq, ROWS);
    hipLaunchKernelGGL(k_gemm_max,     dim3(NRB * NC), dim3(256), 0, stream, query, sn, invq, rowmaxg);
    hipLaunchKernelGGL(k_top6,         dim3(640),      dim3(256), 0, stream, rowmaxg, scale, bias, out);
}

// Round 2
// 452.427 us; speedup vs baseline: 1.1356x; 1.1356x over previous
//
#include <hip/hip_runtime.h>
#include <hip/hip_bf16.h>
#include <cstdint>

typedef __attribute__((ext_vector_type(8))) short short8;
typedef __attribute__((ext_vector_type(4))) float floatx4;

#define NC   5
#define PP   196
#define DD   384
#define MM   512
#define ROWS (MM * PP)     /* 100352 = 1568 * 64 exactly */
#define NRB  1568
#define EPSN 1e-12f
#define ASTR 392           /* As row stride (bf16 elems): 784 B -> 2-way-only bank aliasing */
#define BSTR 40            /* Bs row stride (bf16 elems): 80 B -> 2-way-only bank aliasing */

/* monotone float <-> uint encoding so atomicMax(unsigned) orders like float */
__device__ __forceinline__ unsigned enc_f(float f) {
    unsigned u = __float_as_uint(f);
    return (u & 0x80000000u) ? ~u : (u | 0x80000000u);
}
__device__ __forceinline__ float dec_f(unsigned u) {
    unsigned b = (u & 0x80000000u) ? (u ^ 0x80000000u) : ~u;
    return __uint_as_float(b);
}
#define ENC_NEG_INF 0x007FFFFFu

/* ---- pass 1: l2-normalize support rows -> bf16 (980 x 384) ---- */
__global__ __launch_bounds__(256) void k_norm_support(const float* __restrict__ sup,
                                                      __hip_bfloat16* __restrict__ sn) {
    int wid = threadIdx.x >> 6, lane = threadIdx.x & 63;
    int r = blockIdx.x * 4 + wid;
    if (r >= NC * PP) return;
    const float* src = sup + (size_t)r * DD;
    float x[6]; float s = 0.f;
    #pragma unroll
    for (int j = 0; j < 6; ++j) { x[j] = src[lane + j * 64]; s += x[j] * x[j]; }
    #pragma unroll
    for (int off = 1; off < 64; off <<= 1) s += __shfl_xor(s, off, 64);
    float inv = 1.0f / fmaxf(sqrtf(s), EPSN);
    __hip_bfloat16* dst = sn + (size_t)r * DD;
    #pragma unroll
    for (int j = 0; j < 6; ++j) dst[lane + j * 64] = __float2bfloat16(x[j] * inv);
}

/* ---- main: one block per 64-row query strip; A (64x384 bf16) resident in LDS;
        loop 4 col-tiles of 256 over all 5 classes; fused per-class col-max ---- */
__global__ __launch_bounds__(256, 2) void k_gemm_max(const float* __restrict__ q,
                                                     const __hip_bfloat16* __restrict__ sn,
                                                     float* __restrict__ rowmaxg) {
    __shared__ __hip_bfloat16 As[64 * ASTR];    /* 50176 B */
    __shared__ __hip_bfloat16 Bs[256 * BSTR];   /* 20480 B */
    __shared__ unsigned rmax[64 * NC];          /*  1280 B */
    __shared__ float rss[64];                   /*   256 B */

    const int tid  = threadIdx.x;
    const int row0 = blockIdx.x * 64;
    const int lane = tid & 63;
    const int wav  = tid >> 6;
    const int wc   = wav * 64;                  /* wave col offset inside 256-tile */
    const int quad = lane >> 4, c16 = lane & 15;

    for (int i = tid; i < 64 * NC; i += 256) rmax[i] = ENC_NEG_INF;

    /* ---- B prefetch mapping: thread t covers rows j=(t>>2)+p*64 (p=0..3), ko=(t&3)*8 ---- */
    const int bj0 = tid >> 2;
    const int bko = (tid & 3) * 8;
    uint4 pv[4];

    /* issue first B prefetch (h=0, kk=0) before A staging to overlap */
    #pragma unroll
    for (int p = 0; p < 4; ++p) {
        int g = bj0 + p * 64;                   /* h=0: global col = g */
        pv[p] = make_uint4(0u, 0u, 0u, 0u);
        if (g < NC * PP) pv[p] = *(const uint4*)(sn + (size_t)g * DD + bko);
    }

    /* ---- A staging: fp32 -> bf16 into LDS, fused row sum-of-squares ---- */
    {
        const int arow = tid >> 2;              /* 0..63 */
        const int asub = tid & 3;
        const float* src = q + (size_t)(row0 + arow) * DD;
        float ss = 0.f;
        #pragma unroll
        for (int i = 0; i < 12; ++i) {
            int ch = asub + i * 4;              /* chunk of 8 elems, 0..47 */
            const float4* p = (const float4*)(src + ch * 8);
            float4 x0 = p[0], x1 = p[1];
            ss += x0.x*x0.x + x0.y*x0.y + x0.z*x0.z + x0.w*x0.w
                + x1.x*x1.x + x1.y*x1.y + x1.z*x1.z + x1.w*x1.w;
            alignas(16) __hip_bfloat16 hb[8];
            hb[0] = __float2bfloat16(x0.x); hb[1] = __float2bfloat16(x0.y);
            hb[2] = __float2bfloat16(x0.z); hb[3] = __float2bfloat16(x0.w);
            hb[4] = __float2bfloat16(x1.x); hb[5] = __float2bfloat16(x1.y);
            hb[6] = __float2bfloat16(x1.z); hb[7] = __float2bfloat16(x1.w);
            *(uint4*)&As[arow * ASTR + ch * 8] = *(const uint4*)hb;
        }
        ss += __shfl_xor(ss, 1, 64);
        ss += __shfl_xor(ss, 2, 64);
        if (asub == 0) rss[arow] = ss;
    }

    /* ---- main loop: 4 col-tiles of 256, K in chunks of 32 ---- */
    for (int h = 0; h < 4; ++h) {
        floatx4 acc[4][4];
        #pragma unroll
        for (int i = 0; i < 4; ++i)
            #pragma unroll
            for (int j = 0; j < 4; ++j) acc[i][j] = (floatx4){0.f, 0.f, 0.f, 0.f};

        for (int kk = 0; kk < DD; kk += 32) {
            __syncthreads();                    /* prev compute done; Bs free */
            #pragma unroll
            for (int p = 0; p < 4; ++p)
                *(uint4*)&Bs[(bj0 + p * 64) * BSTR + bko] = pv[p];
            __syncthreads();

            /* prefetch next B slice */
            int nh = h, nkk = kk + 32;
            if (nkk == DD) { nh = h + 1; nkk = 0; }
            if (nh < 4) {
                #pragma unroll
                for (int p = 0; p < 4; ++p) {
                    int g = nh * 256 + bj0 + p * 64;
                    pv[p] = make_uint4(0u, 0u, 0u, 0u);
                    if (g < NC * PP)
                        pv[p] = *(const uint4*)(sn + (size_t)g * DD + nkk + bko);
                }
            }

            /* compute: 16 MFMAs per wave */
            short8 a[4], b[4];
            #pragma unroll
            for (int rt = 0; rt < 4; ++rt)
                a[rt] = *(const short8*)&As[(rt * 16 + c16) * ASTR + kk + quad * 8];
            #pragma unroll
            for (int ct = 0; ct < 4; ++ct)
                b[ct] = *(const short8*)&Bs[(wc + ct * 16 + c16) * BSTR + quad * 8];
            #pragma unroll
            for (int rt = 0; rt < 4; ++rt)
                #pragma unroll
                for (int ct = 0; ct < 4; ++ct)
                    acc[rt][ct] = __builtin_amdgcn_mfma_f32_16x16x32_bf16(
                        a[rt], b[ct], acc[rt][ct], 0, 0, 0);
        }

        /* ---- epilogue: per-class col-max; a 64-col wave footprint spans <=2 classes ---- */
        const int cb0  = h * 256 + wc;          /* first col of this wave's footprint */
        const int cA   = cb0 / PP;              /* class of first col */
        const int bnd  = (cA + 1) * PP;         /* first col of next class */
        const bool hasB = (bnd < cb0 + 64) && (cA + 1 < NC);

        #pragma unroll
        for (int rt = 0; rt < 4; ++rt) {
            #pragma unroll
            for (int reg = 0; reg < 4; ++reg) {
                float mxA = -INFINITY, mxB = -INFINITY;
                #pragma unroll
                for (int ct = 0; ct < 4; ++ct) {
                    int col = cb0 + ct * 16 + c16;
                    float v = acc[rt][ct][reg];
                    if (col < bnd) mxA = fmaxf(mxA, v);        /* bnd<=980 -> valid */
                    else mxB = fmaxf(mxB, (col < NC * PP) ? v : -INFINITY);
                }
                #pragma unroll
                for (int off = 1; off < 16; off <<= 1) {
                    mxA = fmaxf(mxA, __shfl_xor(mxA, off, 64));
                    if (hasB) mxB = fmaxf(mxB, __shfl_xor(mxB, off, 64));
                }
                if (c16 == 0) {
                    int rloc = rt * 16 + quad * 4 + reg;
                    atomicMax(&rmax[rloc * NC + cA], enc_f(mxA));
                    if (hasB) atomicMax(&rmax[rloc * NC + cA + 1], enc_f(mxB));
                }
            }
        }
    }

    __syncthreads();
    for (int i = tid; i < 64 * NC; i += 256) {
        int row = i / NC, c = i % NC;
        float inv = 1.0f / fmaxf(sqrtf(rss[row]), EPSN);
        rowmaxg[(size_t)(row0 + row) * NC + c] = dec_f(rmax[row * NC + c]) * inv;
    }
}

/* ---- top-6 sum per (m, c): one wave each ---- */
__global__ __launch_bounds__(256) void k_top6(const float* __restrict__ rowmaxg,
                                              const float* __restrict__ scale,
                                              const float* __restrict__ bias,
                                              float* __restrict__ out) {
    int wav = threadIdx.x >> 6, lane = threadIdx.x & 63;
    int pair = blockIdx.x * 4 + wav;
    if (pair >= MM * NC) return;
    int m = pair / NC, c = pair % NC;
    size_t base = (size_t)m * PP;
    float v[4];
    #pragma unroll
    for (int i = 0; i < 4; ++i) {
        int p = lane + i * 64;
        v[i] = (p < PP) ? rowmaxg[(base + p) * NC + c] : -INFINITY;
    }
    float sum = 0.f;
    for (int t = 0; t < 6; ++t) {
        float bv = v[0]; int bi = 0;
        #pragma unroll
        for (int i = 1; i < 4; ++i) { if (v[i] > bv) { bv = v[i]; bi = i; } }
        int gid = bi * 64 + lane;
        #pragma unroll
        for (int off = 1; off < 64; off <<= 1) {
            float ov = __shfl_xor(bv, off, 64);
            int og  = __shfl_xor(gid, off, 64);
            if (ov > bv || (ov == bv && og < gid)) { bv = ov; gid = og; }
        }
        sum += bv;
        if ((gid & 63) == lane) v[gid >> 6] = -INFINITY;  /* kill exactly one */
    }
    if (lane == 0) out[pair] = scale[0] * (sum + bias[0]);
}

extern "C" void kernel_launch(void* const* d_in, const int* in_sizes, int n_in,
                              void* d_out, int out_size, void* d_ws, size_t ws_size,
                              hipStream_t stream) {
    const float* support = (const float*)d_in[0];
    const float* query   = (const float*)d_in[1];
    const float* scale   = (const float*)d_in[2];
    const float* bias    = (const float*)d_in[3];
    float* out = (float*)d_out;

    char* ws = (char*)d_ws;
    __hip_bfloat16* sn = (__hip_bfloat16*)ws;              /* 980*384*2 = 752640 -> pad 753664 */
    float* rowmaxg     = (float*)(ws + 753664);            /* 100352*5*4 = 2007040 */

    hipLaunchKernelGGL(k_norm_support, dim3(245),  dim3(256), 0, stream, support, sn);
    hipLaunchKernelGGL(k_gemm_max,     dim3(NRB),  dim3(256), 0, stream, query, sn, rowmaxg);
    hipLaunchKernelGGL(k_top6,         dim3(640),  dim3(256), 0, stream, rowmaxg, scale, bias, out);
}